// Round 2
// baseline (242.850 us; speedup 1.0000x reference)
//
#include <hip/hip_runtime.h>

namespace {

constexpr int B  = 8;
constexpr int L  = 4096;
constexpr int D  = 1024;
constexpr int D4 = D / 4;        // 256 float4 per row
constexpr int P  = L / 2;        // 2048 pair-rows
constexpr int TJ = 32;           // columns per tile (128 B row slice)
constexpr int TP = 64;           // output pairs per tile
constexpr int RP = TP + TJ;      // 96 staged pair-rows (1.5x read redundancy, L2-absorbed)
constexpr int RR = 2 * RP;       // 192 staged RAW rows per tile
constexpr int NT = 512;          // 8 waves
constexpr int NW = NT / 64;
constexpr int T  = 4;            // p-tiles per block, double-buffered pipeline
constexpr int NCH = RR * TJ * 4 / 1024;  // 24 x 1KiB DMA chunks per tile
constexpr int CPW = NCH / NW;            // 3 global_load_lds per thread per tile
static_assert(CPW == 3, "vmcnt literal below assumes 3 in-flight chunk loads");
static_assert(2 * RR * TJ * 4 <= 49152, "LDS must stay well under 64 KiB");

// Async 16B global->LDS DMA. LDS dest is wave-uniform base + lane*16 (linear).
__device__ __forceinline__ void async_ld16(const float* g, float* l) {
  __builtin_amdgcn_global_load_lds(
      (const __attribute__((address_space(1))) void*)g,
      (__attribute__((address_space(3))) void*)l, 16, 0, 0);
}

// out[b, 2p+t, j] = {min,max}(v[b,2q,j], v[b,2q+1,j]), q = (p - h_j) mod P,
// h_j = j-1 (h_0 = 0). Raw rows are DMA-staged double-buffered in LDS; the
// pair min/max fold and the 1-pair-per-column shear resolve at drain.
__global__ __launch_bounds__(NT, 6)
void swd_kernel(const float* __restrict__ v, float4* __restrict__ out) {
  const int j0 = blockIdx.x * TJ;
  const int ty = blockIdx.y;               // handles p-tiles ty*T .. ty*T+T-1
  const int b  = blockIdx.z;

  __shared__ float lds[2][RR * TJ];        // 2 x 24 KiB linear raw-row slices

  const int tid  = threadIdx.x;
  const int wave = tid >> 6;
  const int lane = tid & 63;

  const float* __restrict__ vb = v + (size_t)b * L * D + j0;

  // stage lane geometry: chunk C = wave + NW*i covers raw rows C*8..C*8+7
  const int f  = lane & 7;                 // 16B quad within 128B row slice
  const int kb = wave * 8 + (lane >> 3);   // lane's raw row for i=0

  // drain geometry: thread owns column quad g, output pair pp = c of the tile
  const int g   = tid & 7;
  const int c   = tid >> 3;                // 0..63 = pair within tile
  // pair-row of component x: kx = c + (TJ-1) - 4g; need pair rows kx-3..kx,
  // i.e. raw rows 2*kx-6 .. 2*kx+1:
  const int krb = 2 * c - 8 * g + 2 * (TJ - 1) - 6;   // in [0, 182]
  const bool sp = (j0 == 0) && (g == 0);   // column 0: h_0 = 0, not -1

  float4* __restrict__ ob = out + (size_t)b * L * D4 + (j0 >> 2) + g;

  auto stage = [&](int tt, int s) {
    const int p0 = tt * TP;
    const int r0 = p0 - (j0 + TJ - 2);     // lowest staged pair index (mod P)
#pragma unroll
    for (int i = 0; i < CPW; ++i) {
      const int kr  = kb + 64 * i;         // raw staged row 0..191
      const int q   = (r0 + (kr >> 1)) & (P - 1);
      const int row = 2 * q + (kr & 1);
      async_ld16(vb + (size_t)row * D + 4 * f,
                 &lds[s][(wave + NW * i) * (8 * TJ)]);   // wave-uniform base
    }
  };

  const int tt0 = ty * T;
  stage(tt0, 0);                           // prologue: tile 0 into buffer 0

#pragma unroll
  for (int t = 0; t < T; ++t) {
    if (t + 1 < T) {
      stage(tt0 + t + 1, (t + 1) & 1);     // issue next tile first...
      // ...then wait for tile t only: newest 3 (tile t+1) stay in flight.
      asm volatile("s_waitcnt vmcnt(3)" ::: "memory");
    } else {
      asm volatile("s_waitcnt vmcnt(0)" ::: "memory");
    }
    __builtin_amdgcn_s_barrier();          // all waves' tile-t DMA landed
    asm volatile("" ::: "memory");         // no LDS access hoists above barrier

    const float* Lb = lds[t & 1];

    // pair rows kx-3..kx: read raw pair, fold min/max immediately
    float4 m[4], M[4];
#pragma unroll
    for (int u = 0; u < 4; ++u) {
      const float4 a0 = *(const float4*)&Lb[(krb + 2 * u)     * TJ + 4 * g];
      const float4 a1 = *(const float4*)&Lb[(krb + 2 * u + 1) * TJ + 4 * g];
      m[u].x = fminf(a0.x, a1.x); M[u].x = fmaxf(a0.x, a1.x);
      m[u].y = fminf(a0.y, a1.y); M[u].y = fmaxf(a0.y, a1.y);
      m[u].z = fminf(a0.z, a1.z); M[u].z = fmaxf(a0.z, a1.z);
      m[u].w = fminf(a0.w, a1.w); M[u].w = fmaxf(a0.w, a1.w);
    }

    float4 e, o;
    e.x = sp ? m[2].x : m[3].x; e.y = m[2].y; e.z = m[1].z; e.w = m[0].w;
    o.x = sp ? M[2].x : M[3].x; o.y = M[2].y; o.z = M[1].z; o.w = M[0].w;

    const size_t ro = (size_t)(2 * ((tt0 + t) * TP + c)) * D4;
    ob[ro]      = e;
    ob[ro + D4] = o;

    // all LDS reads of this buffer retired before next iteration's DMA
    // may overwrite it (buffer (t+1)&1 is drained at t-1, restaged at t+1).
    asm volatile("s_waitcnt lgkmcnt(0)" ::: "memory");
    __builtin_amdgcn_s_barrier();
    asm volatile("" ::: "memory");
  }
}

} // namespace

extern "C" void kernel_launch(void* const* d_in, const int* /*in_sizes*/, int /*n_in*/,
                              void* d_out, int /*out_size*/, void* /*d_ws*/, size_t /*ws_size*/,
                              hipStream_t stream) {
  const float* v = (const float*)d_in[0];
  float4* out = (float4*)d_out;
  dim3 grid(D / TJ, P / (T * TP), B);   // (32, 8, 8) = 2048 blocks
  swd_kernel<<<grid, NT, 0, stream>>>(v, out);
}

// Round 3
// 233.520 us; speedup vs baseline: 1.0400x; 1.0400x over previous
//
#include <hip/hip_runtime.h>

namespace {

constexpr int B  = 8;
constexpr int L  = 4096;
constexpr int D  = 1024;
constexpr int D4 = D / 4;        // 256 float4 per row
constexpr int P  = L / 2;        // 2048 pair-rows
constexpr int TJ = 64;           // columns per block (256 B row slice)
constexpr int TP = 32;           // output pairs per block
constexpr int RP = TP + TJ;      // 96 staged pair-rows (3x read redundancy, LLC-absorbed)
constexpr int RR = 2 * RP;       // 192 staged RAW rows
constexpr int NT = 512;          // 8 waves
constexpr int NW = NT / 64;
constexpr int NCH = RR * TJ * 4 / 1024;  // 48 x 1KiB DMA chunks (4 raw rows each)
constexpr int CPW = NCH / NW;            // 6 chunks per wave
static_assert(CPW == 6, "chunk math");
static_assert(RR * TJ * 4 == 48 * 1024, "LDS = 48 KiB, 3 blocks/CU");

// Async 16B global->LDS DMA. LDS dest is wave-uniform base + lane*16 (linear).
__device__ __forceinline__ void async_ld16(const float* g, float* l) {
  __builtin_amdgcn_global_load_lds(
      (const __attribute__((address_space(1))) void*)g,
      (__attribute__((address_space(3))) void*)l, 16, 0, 0);
}

// out[b, 2p+t, j] = {min,max}(v[b,2q,j], v[b,2q+1,j]), q = (p - h_j) mod P,
// h_j = j-1 (h_0 = 0). 256 B row slices staged raw in LDS (one tile, 2-phase);
// pair min/max fold and the 1-pair-per-column shear resolve at drain.
__global__ __launch_bounds__(NT, 6)
void swd_kernel(const float* __restrict__ v, float4* __restrict__ out) {
  const int j0 = blockIdx.x * TJ;
  const int p0 = blockIdx.y * TP;
  const int b  = blockIdx.z;

  __shared__ float lds[RR * TJ];   // raw row r lives at [r*TJ, r*TJ+TJ)

  const int tid  = threadIdx.x;
  const int wave = tid >> 6;
  const int lane = tid & 63;

  const float* __restrict__ vb = v + (size_t)b * L * D + j0;
  const int r0 = p0 - (j0 + TJ - 2);     // lowest staged pair index (mod P)

  // ---- Stage: chunk C = wave + NW*i covers raw rows 4C..4C+3 (256 B slices)
  const int f  = lane & 15;              // 16 B quad within 256 B row slice
  const int rc = lane >> 4;              // raw row within chunk
#pragma unroll
  for (int i = 0; i < CPW; ++i) {
    const int C   = wave + NW * i;       // 1 KiB chunk index, wave-uniform
    const int kr  = 4 * C + rc;          // raw staged row 0..191
    const int q   = (r0 + (kr >> 1)) & (P - 1);
    const int row = 2 * q + (kr & 1);
    async_ld16(vb + (size_t)row * D + 4 * f, &lds[C * 256]);
  }
  asm volatile("s_waitcnt vmcnt(0)" ::: "memory");
  __syncthreads();

  // ---- Drain: thread owns column quad g (0..15), output pair c (0..31).
  const int g = tid & 15;
  const int c = tid >> 4;
  // pair-row (window index) for component x: K0 = c + (TJ-1) - 4g;
  // components x,y,z,w use pairs K0, K0-1, K0-2, K0-3 -> raw rows krb..krb+7.
  const int krb = 2 * c - 8 * g + 2 * (TJ - 1) - 6;   // in [0, 182]
  const bool sp = (j0 == 0) && (g == 0);  // column 0: h_0 = 0, not -1

  float4 m[4], M[4];
#pragma unroll
  for (int u = 0; u < 4; ++u) {
    const float4 a0 = *(const float4*)&lds[(krb + 2 * u)     * TJ + 4 * g];
    const float4 a1 = *(const float4*)&lds[(krb + 2 * u + 1) * TJ + 4 * g];
    m[u].x = fminf(a0.x, a1.x); M[u].x = fmaxf(a0.x, a1.x);
    m[u].y = fminf(a0.y, a1.y); M[u].y = fmaxf(a0.y, a1.y);
    m[u].z = fminf(a0.z, a1.z); M[u].z = fmaxf(a0.z, a1.z);
    m[u].w = fminf(a0.w, a1.w); M[u].w = fmaxf(a0.w, a1.w);
  }

  float4 e, o;
  e.x = sp ? m[2].x : m[3].x; e.y = m[2].y; e.z = m[1].z; e.w = m[0].w;
  o.x = sp ? M[2].x : M[3].x; o.y = M[2].y; o.z = M[1].z; o.w = M[0].w;

  float4* __restrict__ ob = out + (size_t)b * L * D4 + (j0 >> 2) + g;
  const size_t ro = (size_t)(2 * (p0 + c)) * D4;
  ob[ro]      = e;    // row 2p   : lanes g=0..15 form 256 B contiguous
  ob[ro + D4] = o;    // row 2p+1
}

} // namespace

extern "C" void kernel_launch(void* const* d_in, const int* /*in_sizes*/, int /*n_in*/,
                              void* d_out, int /*out_size*/, void* /*d_ws*/, size_t /*ws_size*/,
                              hipStream_t stream) {
  const float* v = (const float*)d_in[0];
  float4* out = (float4*)d_out;
  dim3 grid(D / TJ, P / TP, B);   // (16, 64, 8) = 8192 blocks
  swd_kernel<<<grid, NT, 0, stream>>>(v, out);
}